// Round 10
// baseline (42.024 us; speedup 1.0000x reference)
//
#include <hip/hip_runtime.h>

#define CC 64
#define HH 64
#define WW 64
#define OO 128
#define HW (HH * WW)

typedef float f32x4 __attribute__((ext_vector_type(4)));

// lane L (within a 16-lane DPP row) gets src from lane L-1; first lane keeps edge.
__device__ __forceinline__ float dpp_shr1(float src, float edge) {
    int old = __builtin_bit_cast(int, edge);
    int s   = __builtin_bit_cast(int, src);
    int r = __builtin_amdgcn_update_dpp(old, s, 0x111, 0xF, 0xF, false); // row_shr:1
    return __builtin_bit_cast(float, r);
}
// lane L gets src from lane L+1; last lane of each 16-lane row keeps edge.
__device__ __forceinline__ float dpp_shl1(float src, float edge) {
    int old = __builtin_bit_cast(int, edge);
    int s   = __builtin_bit_cast(int, src);
    int r = __builtin_amdgcn_update_dpp(old, s, 0x101, 0xF, 0xF, false); // row_shl:1
    return __builtin_bit_cast(float, r);
}

// Persistent-ish blocks: 512 blocks (2/CU), each handles 4 tiles
// (tile = it*512 + bid). region = tile&63 stays constant per block while
// ochunk steps by 8 -> iterations re-hit the same x slab in L2/L1.
// Inner loop = R3 structure: 16 rows x 16 lanes, lane owns cols 4L..4L+3,
// float4 tap gathers (1KB/wave), DPP edge exchange, 4-o unrolled DAG,
// nontemporal float4 stores (out stream doesn't evict x from L2).
__global__ __launch_bounds__(256) void minimax_conv_kernel(
    const float* __restrict__ x, const float* __restrict__ w1,
    const float* __restrict__ w2, const int* __restrict__ conn,
    float* __restrict__ out)
{
    const int tid  = threadIdx.x;
    const int L    = tid & 15;        // column group within row
    const int hrow = tid >> 4;        // 0..15 row within block
    const int bid  = blockIdx.x;

    const int region = bid & 63;      // constant across iterations
    const int b  = region >> 2;
    const int h0 = (region & 3) * 16;
    const int h  = h0 + hrow;

    // per-lane clamped row offsets (elements) for kernel row i = 0,1,2
    int r0i = h - 1;     r0i = r0i < 0 ? 0 : r0i;
    int r2i = h + 1;     r2i = r2i > HH - 1 ? HH - 1 : r2i;
    const int ro0 = r0i * WW + 4 * L;
    const int ro1 = h   * WW + 4 * L;
    const int ro2 = r2i * WW + 4 * L;

    const float* xb = x + (size_t)b * (CC * HW);
    float* outb0 = out + (((size_t)b * OO) * HH + h) * WW + 4 * L;

    for (int it = 0; it < 4; ++it) {
        const int tile = it * 512 + bid;
        const int ochunk = tile >> 6;          // 0..31, steps by 8 per it
        const int ob = ochunk * 4;
        float* outb = outb0 + (size_t)ob * HW;

        #pragma unroll
        for (int oi = 0; oi < 4; ++oi) {
            const int o = ob + oi;             // wave-uniform

            float4 q[9];
            int    j[9];
            #pragma unroll
            for (int t = 0; t < 9; ++t) {
                const int v  = conn[o * 9 + t];    // uniform -> s_load
                const int c  = v / 9;
                const int r9 = v - c * 9;
                const int i  = r9 / 3;
                j[t] = r9 - i * 3;
                const int ro = (i == 0) ? ro0 : ((i == 1) ? ro1 : ro2);
                q[t] = *(const float4*)(xb + c * HW + ro);   // 1KB wave gather
            }

            float r0, r1, r2, r3;
            #pragma unroll
            for (int p = 0; p < 3; ++p) {
                float e0, e1, e2, e3;
                #pragma unroll
                for (int tt = 0; tt < 3; ++tt) {
                    const int t = p * 3 + tt;
                    const float w1v = w1[o * 9 + t];           // uniform
                    const float4 qq = q[t];
                    float v0, v1, v2, v3;
                    if (j[t] == 0) {                           // uniform branch
                        const float le = dpp_shr1(qq.w, qq.x);
                        v0 = le;   v1 = qq.x; v2 = qq.y; v3 = qq.z;
                    } else if (j[t] == 1) {
                        v0 = qq.x; v1 = qq.y; v2 = qq.z; v3 = qq.w;
                    } else {
                        const float re = dpp_shl1(qq.x, qq.w);
                        v0 = qq.y; v1 = qq.z; v2 = qq.w; v3 = re;
                    }
                    const float d0 = fabsf(v0 - w1v);
                    const float d1 = fabsf(v1 - w1v);
                    const float d2 = fabsf(v2 - w1v);
                    const float d3 = fabsf(v3 - w1v);
                    if (tt == 0) { e0 = d0; e1 = d1; e2 = d2; e3 = d3; }
                    else {
                        e0 = fmaxf(e0, d0); e1 = fmaxf(e1, d1);
                        e2 = fmaxf(e2, d2); e3 = fmaxf(e3, d3);
                    }
                }
                const float w2v = w2[o * 3 + p];               // uniform
                const float m0 = fabsf(e0 - w2v);
                const float m1 = fabsf(e1 - w2v);
                const float m2 = fabsf(e2 - w2v);
                const float m3 = fabsf(e3 - w2v);
                if (p == 0) { r0 = m0; r1 = m1; r2 = m2; r3 = m3; }
                else {
                    r0 = fminf(r0, m0); r1 = fminf(r1, m1);
                    r2 = fminf(r2, m2); r3 = fminf(r3, m3);
                }
            }

            f32x4 res; res.x = r0; res.y = r1; res.z = r2; res.w = r3;
            __builtin_nontemporal_store(res, (f32x4*)(outb + (size_t)oi * HW));
        }
    }
}

extern "C" void kernel_launch(void* const* d_in, const int* in_sizes, int n_in,
                              void* d_out, int out_size, void* d_ws, size_t ws_size,
                              hipStream_t stream) {
    const float* x    = (const float*)d_in[0];
    const float* w1   = (const float*)d_in[1];
    const float* w2   = (const float*)d_in[2];
    const int*   conn = (const int*)d_in[3];
    float* out = (float*)d_out;

    const int blocks = 512;   // 2 per CU, each does 4 tiles
    minimax_conv_kernel<<<blocks, 256, 0, stream>>>(x, w1, w2, conn, out);
}

// Round 11
// 33.295 us; speedup vs baseline: 1.2622x; 1.2622x over previous
//
#include <hip/hip_runtime.h>

#define BB 16
#define CC 64
#define HH 64
#define WW 64
#define OO 128
#define HW (HH * WW)
#define NX (BB * CC * HH * WW)      // 4194304 x elements

typedef float f32x4 __attribute__((ext_vector_type(4)));

// lane L (within a 16-lane DPP row) gets src from lane L-1; first lane keeps edge.
__device__ __forceinline__ float dpp_shr1(float src, float edge) {
    int old = __builtin_bit_cast(int, edge);
    int s   = __builtin_bit_cast(int, src);
    int r = __builtin_amdgcn_update_dpp(old, s, 0x111, 0xF, 0xF, false); // row_shr:1
    return __builtin_bit_cast(float, r);
}
// lane L gets src from lane L+1; last lane of each 16-lane row keeps edge.
__device__ __forceinline__ float dpp_shl1(float src, float edge) {
    int old = __builtin_bit_cast(int, edge);
    int s   = __builtin_bit_cast(int, src);
    int r = __builtin_amdgcn_update_dpp(old, s, 0x101, 0xF, 0xF, false); // row_shl:1
    return __builtin_bit_cast(float, r);
}

__device__ __forceinline__ unsigned pack_bf16(float lo, float hi) {
    // truncating f32->bf16 (error <= 2^-8 relative; threshold is 7.9e-2)
    unsigned a = __builtin_bit_cast(unsigned, lo);
    unsigned b = __builtin_bit_cast(unsigned, hi);
    return (a >> 16) | (b & 0xFFFF0000u);
}

// ---- kernel 1: x fp32 -> bf16 (packed pairs), 8 elems/thread ----
__global__ __launch_bounds__(256) void cvt_bf16_kernel(
    const float* __restrict__ x, unsigned* __restrict__ xb)
{
    const int t = blockIdx.x * 256 + threadIdx.x;       // 524288 threads
    const f32x4 a = __builtin_nontemporal_load((const f32x4*)x + 2 * t);
    const f32x4 bq = __builtin_nontemporal_load((const f32x4*)x + 2 * t + 1);
    uint4 r;
    r.x = pack_bf16(a.x,  a.y);
    r.y = pack_bf16(a.z,  a.w);
    r.z = pack_bf16(bq.x, bq.y);
    r.w = pack_bf16(bq.z, bq.w);
    ((uint4*)xb)[t] = r;    // regular store: keep slab L2-resident (~1MB/XCD)
}

// ---- kernel 2: R3 structure, bf16x4 (uint2, 8B) tap gathers ----
// Block: 256 thr = 16 rows x 16 lanes; lane owns cols 4L..4L+3.
// Grid: 2048 = 32 o-chunks * 64 regions; XCD = region % 8.
__global__ __launch_bounds__(256) void minimax_conv_bf16_kernel(
    const unsigned short* __restrict__ xb16, const float* __restrict__ w1,
    const float* __restrict__ w2, const int* __restrict__ conn,
    float* __restrict__ out)
{
    const int tid  = threadIdx.x;
    const int L    = tid & 15;
    const int hrow = tid >> 4;
    const int bid = blockIdx.x;
    const int ochunk = bid >> 6;
    const int region = bid & 63;
    const int b  = region >> 2;
    const int h0 = (region & 3) * 16;
    const int h  = h0 + hrow;

    int r0i = h - 1;     r0i = r0i < 0 ? 0 : r0i;
    int r2i = h + 1;     r2i = r2i > HH - 1 ? HH - 1 : r2i;
    const int ro0 = r0i * WW + 4 * L;
    const int ro1 = h   * WW + 4 * L;
    const int ro2 = r2i * WW + 4 * L;

    const unsigned short* xb = xb16 + (size_t)b * (CC * HW);
    const int ob = ochunk * 4;
    float* outb = out + (((size_t)b * OO + ob) * HH + h) * WW + 4 * L;

    #pragma unroll
    for (int oi = 0; oi < 4; ++oi) {
        const int o = ob + oi;                 // wave-uniform

        uint2 q[9];
        int   j[9];
        #pragma unroll
        for (int t = 0; t < 9; ++t) {
            const int v  = conn[o * 9 + t];    // uniform -> s_load
            const int c  = v / 9;
            const int r9 = v - c * 9;
            const int i  = r9 / 3;
            j[t] = r9 - i * 3;
            const int ro = (i == 0) ? ro0 : ((i == 1) ? ro1 : ro2);
            q[t] = *(const uint2*)(xb + c * HW + ro);   // 512B wave gather (8 lines)
        }

        float r0, r1, r2, r3;
        #pragma unroll
        for (int p = 0; p < 3; ++p) {
            float e0, e1, e2, e3;
            #pragma unroll
            for (int tt = 0; tt < 3; ++tt) {
                const int t = p * 3 + tt;
                const float w1v = w1[o * 9 + t];       // uniform
                // unpack bf16x4 -> f32
                const float f0 = __builtin_bit_cast(float, q[t].x << 16);
                const float f1 = __builtin_bit_cast(float, q[t].x & 0xFFFF0000u);
                const float f2 = __builtin_bit_cast(float, q[t].y << 16);
                const float f3 = __builtin_bit_cast(float, q[t].y & 0xFFFF0000u);
                float v0, v1, v2, v3;
                if (j[t] == 0) {                       // uniform branch
                    const float le = dpp_shr1(f3, f0);
                    v0 = le; v1 = f0; v2 = f1; v3 = f2;
                } else if (j[t] == 1) {
                    v0 = f0; v1 = f1; v2 = f2; v3 = f3;
                } else {
                    const float re = dpp_shl1(f0, f3);
                    v0 = f1; v1 = f2; v2 = f3; v3 = re;
                }
                const float d0 = fabsf(v0 - w1v);
                const float d1 = fabsf(v1 - w1v);
                const float d2 = fabsf(v2 - w1v);
                const float d3 = fabsf(v3 - w1v);
                if (tt == 0) { e0 = d0; e1 = d1; e2 = d2; e3 = d3; }
                else {
                    e0 = fmaxf(e0, d0); e1 = fmaxf(e1, d1);
                    e2 = fmaxf(e2, d2); e3 = fmaxf(e3, d3);
                }
            }
            const float w2v = w2[o * 3 + p];           // uniform
            const float m0 = fabsf(e0 - w2v);
            const float m1 = fabsf(e1 - w2v);
            const float m2 = fabsf(e2 - w2v);
            const float m3 = fabsf(e3 - w2v);
            if (p == 0) { r0 = m0; r1 = m1; r2 = m2; r3 = m3; }
            else {
                r0 = fminf(r0, m0); r1 = fminf(r1, m1);
                r2 = fminf(r2, m2); r3 = fminf(r3, m3);
            }
        }

        f32x4 res; res.x = r0; res.y = r1; res.z = r2; res.w = r3;
        __builtin_nontemporal_store(res, (f32x4*)(outb + (size_t)oi * HW));
    }
}

// ---- fallback: fp32 gathers (R3 kernel), used only if ws too small ----
__global__ __launch_bounds__(256) void minimax_conv_f32_kernel(
    const float* __restrict__ x, const float* __restrict__ w1,
    const float* __restrict__ w2, const int* __restrict__ conn,
    float* __restrict__ out)
{
    const int tid  = threadIdx.x;
    const int L    = tid & 15;
    const int hrow = tid >> 4;
    const int bid = blockIdx.x;
    const int ochunk = bid >> 6;
    const int region = bid & 63;
    const int b  = region >> 2;
    const int h0 = (region & 3) * 16;
    const int h  = h0 + hrow;

    int r0i = h - 1;     r0i = r0i < 0 ? 0 : r0i;
    int r2i = h + 1;     r2i = r2i > HH - 1 ? HH - 1 : r2i;
    const int ro0 = r0i * WW + 4 * L;
    const int ro1 = h   * WW + 4 * L;
    const int ro2 = r2i * WW + 4 * L;

    const float* xb = x + (size_t)b * (CC * HW);
    const int ob = ochunk * 4;
    float* outb = out + (((size_t)b * OO + ob) * HH + h) * WW + 4 * L;

    #pragma unroll
    for (int oi = 0; oi < 4; ++oi) {
        const int o = ob + oi;
        float4 q[9];
        int    j[9];
        #pragma unroll
        for (int t = 0; t < 9; ++t) {
            const int v  = conn[o * 9 + t];
            const int c  = v / 9;
            const int r9 = v - c * 9;
            const int i  = r9 / 3;
            j[t] = r9 - i * 3;
            const int ro = (i == 0) ? ro0 : ((i == 1) ? ro1 : ro2);
            q[t] = *(const float4*)(xb + c * HW + ro);
        }
        float r0, r1, r2, r3;
        #pragma unroll
        for (int p = 0; p < 3; ++p) {
            float e0, e1, e2, e3;
            #pragma unroll
            for (int tt = 0; tt < 3; ++tt) {
                const int t = p * 3 + tt;
                const float w1v = w1[o * 9 + t];
                const float4 qq = q[t];
                float v0, v1, v2, v3;
                if (j[t] == 0) {
                    const float le = dpp_shr1(qq.w, qq.x);
                    v0 = le;   v1 = qq.x; v2 = qq.y; v3 = qq.z;
                } else if (j[t] == 1) {
                    v0 = qq.x; v1 = qq.y; v2 = qq.z; v3 = qq.w;
                } else {
                    const float re = dpp_shl1(qq.x, qq.w);
                    v0 = qq.y; v1 = qq.z; v2 = qq.w; v3 = re;
                }
                const float d0 = fabsf(v0 - w1v);
                const float d1 = fabsf(v1 - w1v);
                const float d2 = fabsf(v2 - w1v);
                const float d3 = fabsf(v3 - w1v);
                if (tt == 0) { e0 = d0; e1 = d1; e2 = d2; e3 = d3; }
                else {
                    e0 = fmaxf(e0, d0); e1 = fmaxf(e1, d1);
                    e2 = fmaxf(e2, d2); e3 = fmaxf(e3, d3);
                }
            }
            const float w2v = w2[o * 3 + p];
            const float m0 = fabsf(e0 - w2v);
            const float m1 = fabsf(e1 - w2v);
            const float m2 = fabsf(e2 - w2v);
            const float m3 = fabsf(e3 - w2v);
            if (p == 0) { r0 = m0; r1 = m1; r2 = m2; r3 = m3; }
            else {
                r0 = fminf(r0, m0); r1 = fminf(r1, m1);
                r2 = fminf(r2, m2); r3 = fminf(r3, m3);
            }
        }
        f32x4 res; res.x = r0; res.y = r1; res.z = r2; res.w = r3;
        __builtin_nontemporal_store(res, (f32x4*)(outb + (size_t)oi * HW));
    }
}

extern "C" void kernel_launch(void* const* d_in, const int* in_sizes, int n_in,
                              void* d_out, int out_size, void* d_ws, size_t ws_size,
                              hipStream_t stream) {
    const float* x    = (const float*)d_in[0];
    const float* w1   = (const float*)d_in[1];
    const float* w2   = (const float*)d_in[2];
    const int*   conn = (const int*)d_in[3];
    float* out = (float*)d_out;

    if (ws_size >= (size_t)NX * 2) {
        unsigned* xb = (unsigned*)d_ws;
        cvt_bf16_kernel<<<2048, 256, 0, stream>>>(x, xb);
        minimax_conv_bf16_kernel<<<2048, 256, 0, stream>>>(
            (const unsigned short*)xb, w1, w2, conn, out);
    } else {
        minimax_conv_f32_kernel<<<2048, 256, 0, stream>>>(x, w1, w2, conn, out);
    }
}